// Round 2
// baseline (162.990 us; speedup 1.0000x reference)
//
#include <hip/hip_runtime.h>

// LSTM classifier single step: B=65536, IN=64, H=128, OUT=2.
// bias_kernel folds bx + h0@Wh.T into d_ws (ws re-poison fill is harness-fixed,
// so using d_ws is free — verified R0 vs R1: C ~94us either way).
// lstm_kernel: 4-gate x@Wx.T with bf16 MFMA (16x16x32), fused elementwise +
// OUT=2 projection. R2: grid 1024 x ITERS 4 (4 blocks/CU, 16 waves/CU vs 8),
// c0 staged via LDS with coalesced float4 loads (was 8 scalar gathers/lane),
// x+c0 register prefetch, float2 out store. Kernel is HBM-bound in theory
// (~51 MB -> ~8us); R1 measured 52us at 6.6% HBM = latency-bound.

#define B_SIZE 65536

typedef __bf16 bf16x8 __attribute__((ext_vector_type(8)));
typedef __bf16 bf16x4 __attribute__((ext_vector_type(4)));
typedef float f32x4 __attribute__((ext_vector_type(4)));

__device__ __forceinline__ float fsig(float x) {
    float e = __builtin_amdgcn_exp2f(-1.442695040888963f * x);
    return __builtin_amdgcn_rcpf(1.0f + e);
}
__device__ __forceinline__ float ftanh(float x) {
    float e = __builtin_amdgcn_exp2f(2.885390081777927f * x);
    return 1.0f - 2.0f * __builtin_amdgcn_rcpf(e + 1.0f);
}

// bias512[g*128+r] = bx_g[r] + sum_k h0[k] * Wh_g[r][k]
__global__ void bias_kernel(const float* __restrict__ h0,
                            const float* __restrict__ Whf, const float* __restrict__ Whi,
                            const float* __restrict__ Who, const float* __restrict__ Whc,
                            const float* __restrict__ bxf, const float* __restrict__ bxi,
                            const float* __restrict__ bxo, const float* __restrict__ bxc,
                            float* __restrict__ bias512) {
    int j = blockIdx.x * 64 + threadIdx.x;   // 8 blocks x 64 threads = 512
    int g = j >> 7, r = j & 127;
    const float* Wh = (g == 0) ? Whf : (g == 1) ? Whi : (g == 2) ? Who : Whc;
    const float* bx = (g == 0) ? bxf : (g == 1) ? bxi : (g == 2) ? bxo : bxc;
    float s = bx[r];
    const float4* row = (const float4*)(Wh + r * 128);
    const float4* h4  = (const float4*)h0;
#pragma unroll 8
    for (int k = 0; k < 32; ++k) {
        float4 a = row[k], b = h4[k];
        s += a.x * b.x + a.y * b.y + a.z * b.z + a.w * b.w;
    }
    bias512[j] = s;
}

__launch_bounds__(256, 4)
__global__ void lstm_kernel(const float* __restrict__ x, const float* __restrict__ c0,
                            const float* __restrict__ Wxf, const float* __restrict__ Wxi,
                            const float* __restrict__ Wxo, const float* __restrict__ Wxc,
                            const float* __restrict__ Wy, const float* __restrict__ by,
                            const float* __restrict__ bias512, float* __restrict__ out) {
    __shared__ __bf16 xs[1024];          // 16 rows x 64 k of x, A-fragment layout
    __shared__ float cs[16 * 132];       // 16 rows x 128 cols of c0, +4 pad/row
    __shared__ float yred[4][16][2];     // per-wave partial y

    const int tid  = threadIdx.x;
    const int lane = tid & 63;
    const int w    = tid >> 6;           // wave 0..3 -> hidden cols [w*32, w*32+32)
    const int q    = lane >> 4;          // quad: rows q*4..q*4+3 of the 16-row tile
    const int n15  = lane & 15;          // col within 16-col tile

    // ---- per-wave weight fragments (held in registers all kernel) ----
    const float* Wxg[4] = {Wxf, Wxi, Wxo, Wxc};
    bf16x8 bw[4][2][2];                  // [gate][colblock][kstep]
    float biasv[4][2];
#pragma unroll
    for (int g = 0; g < 4; ++g) {
#pragma unroll
        for (int cb = 0; cb < 2; ++cb) {
            const int n = w * 32 + cb * 16 + n15;    // hidden unit index
            biasv[g][cb] = bias512[g * 128 + n];
#pragma unroll
            for (int kb = 0; kb < 2; ++kb) {
                // B[k][n] = Wx_g[n][k]; lane holds k = kb*32 + q*8 + j
                const float* p = Wxg[g] + n * 64 + kb * 32 + q * 8;
                float4 lo = *(const float4*)p;
                float4 hi = *(const float4*)(p + 4);
                bf16x8 v;
                v[0] = (__bf16)lo.x; v[1] = (__bf16)lo.y; v[2] = (__bf16)lo.z; v[3] = (__bf16)lo.w;
                v[4] = (__bf16)hi.x; v[5] = (__bf16)hi.y; v[6] = (__bf16)hi.z; v[7] = (__bf16)hi.w;
                bw[g][cb][kb] = v;
            }
        }
    }
    float wyv[2][2];
#pragma unroll
    for (int o = 0; o < 2; ++o)
#pragma unroll
        for (int cb = 0; cb < 2; ++cb)
            wyv[o][cb] = Wy[o * 128 + w * 32 + cb * 16 + n15];
    const float by0 = by[0], by1 = by[1];

    constexpr int ITERS = (B_SIZE / 16) / 1024;  // 4 tiles of 16 rows per block
    const int tile0 = blockIdx.x * ITERS;        // contiguous 64 rows per block

    // x staging: thread t loads float4 of row (t>>4), k4=(t&15)*4 ; LDS index in
    // A-frag order: elem(m,k) -> (k>>5)*512 + ((k&31)>>3)*128 + m*8 + (k&7)
    const int xrow = tid >> 4;
    const int k4   = (tid & 15) * 4;
    const int sidx = (k4 >> 5) * 512 + ((k4 & 31) >> 3) * 128 + xrow * 8 + (k4 & 7);

    // c0 staging: thread t loads 8 consecutive floats of row (t>>4), cols (t&15)*8
    const int ccol = (tid & 15) * 8;
    const int cidx = xrow * 132 + ccol;

    float4 xr = *(const float4*)(x + (size_t)(tile0 * 16 + xrow) * 64 + k4);
    float4 cpa = *(const float4*)(c0 + (size_t)(tile0 * 16 + xrow) * 128 + ccol);
    float4 cpb = *(const float4*)(c0 + (size_t)(tile0 * 16 + xrow) * 128 + ccol + 4);
    {
        bf16x4 v; v[0] = (__bf16)xr.x; v[1] = (__bf16)xr.y; v[2] = (__bf16)xr.z; v[3] = (__bf16)xr.w;
        *(bf16x4*)&xs[sidx] = v;
        *(float4*)&cs[cidx] = cpa;
        *(float4*)&cs[cidx + 4] = cpb;
    }
    __syncthreads();

    for (int it = 0; it < ITERS; ++it) {
        const int tile = tile0 + it;
        const int b0 = tile * 16;

        // A fragments (shared by all 4 waves)
        bf16x8 a0 = *(const bf16x8*)&xs[lane * 8];
        bf16x8 a1 = *(const bf16x8*)&xs[512 + lane * 8];

        // c0 from LDS: lane needs (row q*4+r, col w*32+cb*16+n15); 2-way bank alias (free)
        float c0v[2][4];
#pragma unroll
        for (int cb = 0; cb < 2; ++cb)
#pragma unroll
            for (int r = 0; r < 4; ++r)
                c0v[cb][r] = cs[(q * 4 + r) * 132 + w * 32 + cb * 16 + n15];

        // prefetch next x / c0 tile into registers
        const int tn = (it + 1 < ITERS) ? (tile + 1) : tile;
        xr  = *(const float4*)(x  + (size_t)(tn * 16 + xrow) * 64 + k4);
        cpa = *(const float4*)(c0 + (size_t)(tn * 16 + xrow) * 128 + ccol);
        cpb = *(const float4*)(c0 + (size_t)(tn * 16 + xrow) * 128 + ccol + 4);

        // MFMA: acc initialized with bias (bias depends only on col)
        f32x4 acc[4][2];
#pragma unroll
        for (int g = 0; g < 4; ++g)
#pragma unroll
            for (int cb = 0; cb < 2; ++cb) {
                float b = biasv[g][cb];
                f32x4 t = {b, b, b, b};
                acc[g][cb] = t;
            }
#pragma unroll
        for (int g = 0; g < 4; ++g)
#pragma unroll
            for (int cb = 0; cb < 2; ++cb) {
                acc[g][cb] = __builtin_amdgcn_mfma_f32_16x16x32_bf16(a0, bw[g][cb][0], acc[g][cb], 0, 0, 0);
                acc[g][cb] = __builtin_amdgcn_mfma_f32_16x16x32_bf16(a1, bw[g][cb][1], acc[g][cb], 0, 0, 0);
            }

        // elementwise epilogue; C/D layout: col=lane&15, row=q*4+reg
        float p0[4] = {0.f, 0.f, 0.f, 0.f};
        float p1[4] = {0.f, 0.f, 0.f, 0.f};
#pragma unroll
        for (int cb = 0; cb < 2; ++cb)
#pragma unroll
            for (int r = 0; r < 4; ++r) {
                float fg = fsig(acc[0][cb][r]);
                float ig = fsig(acc[1][cb][r]);
                float og = fsig(acc[2][cb][r]);
                float ct = ftanh(acc[3][cb][r]);
                float c  = fg * c0v[cb][r] + ig * ct;
                float h  = og * ftanh(c);
                p0[r] += h * wyv[0][cb];
                p1[r] += h * wyv[1][cb];
            }
        // reduce over the 16 lanes of each quad group (cols of this wave)
#pragma unroll
        for (int m = 1; m < 16; m <<= 1) {
#pragma unroll
            for (int r = 0; r < 4; ++r) {
                p0[r] += __shfl_xor(p0[r], m, 64);
                p1[r] += __shfl_xor(p1[r], m, 64);
            }
        }
        if (n15 == 0) {
#pragma unroll
            for (int r = 0; r < 4; ++r) {
                yred[w][q * 4 + r][0] = p0[r];
                yred[w][q * 4 + r][1] = p1[r];
            }
        }
        __syncthreads();
        if (tid < 16) {
            int row = tid;
            float s0 = by0 + yred[0][row][0] + yred[1][row][0] + yred[2][row][0] + yred[3][row][0];
            float s1 = by1 + yred[0][row][1] + yred[1][row][1] + yred[2][row][1] + yred[3][row][1];
            float2 s = {s0, s1};
            *(float2*)(out + (size_t)(b0 + row) * 2) = s;
        }
        // stage next tile (xs/cs fully consumed before barrier above)
        {
            bf16x4 v; v[0] = (__bf16)xr.x; v[1] = (__bf16)xr.y; v[2] = (__bf16)xr.z; v[3] = (__bf16)xr.w;
            *(bf16x4*)&xs[sidx] = v;
            *(float4*)&cs[cidx] = cpa;
            *(float4*)&cs[cidx + 4] = cpb;
        }
        __syncthreads();
    }
}

extern "C" void kernel_launch(void* const* d_in, const int* in_sizes, int n_in,
                              void* d_out, int out_size, void* d_ws, size_t ws_size,
                              hipStream_t stream) {
    // setup_inputs order: x, h0, c0, [Wxf,bxf,Whf], [Wxi,bxi,Whi], [Wxo,bxo,Who],
    //                     [Wxc,bxc,Whc], Wy, by
    const float* x   = (const float*)d_in[0];
    const float* h0  = (const float*)d_in[1];
    const float* c0  = (const float*)d_in[2];
    const float* Wxf = (const float*)d_in[3];
    const float* bxf = (const float*)d_in[4];
    const float* Whf = (const float*)d_in[5];
    const float* Wxi = (const float*)d_in[6];
    const float* bxi = (const float*)d_in[7];
    const float* Whi = (const float*)d_in[8];
    const float* Wxo = (const float*)d_in[9];
    const float* bxo = (const float*)d_in[10];
    const float* Who = (const float*)d_in[11];
    const float* Wxc = (const float*)d_in[12];
    const float* bxc = (const float*)d_in[13];
    const float* Whc = (const float*)d_in[14];
    const float* Wy  = (const float*)d_in[15];
    const float* by  = (const float*)d_in[16];
    float* out = (float*)d_out;
    float* bias512 = (float*)d_ws;   // 512 floats scratch

    bias_kernel<<<8, 64, 0, stream>>>(h0, Whf, Whi, Who, Whc, bxf, bxi, bxo, bxc, bias512);
    lstm_kernel<<<1024, 256, 0, stream>>>(x, c0, Wxf, Wxi, Wxo, Wxc, Wy, by, bias512, out);
}

// Round 3
// 135.975 us; speedup vs baseline: 1.1987x; 1.1987x over previous
//
#include <hip/hip_runtime.h>

// LSTM classifier single step: B=65536, IN=64, H=128, OUT=2.
// bias_kernel folds bx + h0@Wh.T into d_ws (256 MiB ws re-poison fill is
// harness-fixed ~94us — verified R1: dur 146 = 94 + lstm 52 with ws unused).
// lstm_kernel: 4-gate x@Wx.T with bf16 MFMA (16x16x32), fused elementwise +
// OUT=2 projection. R3: launch_bounds(256,2) — R2's (256,4) forced VGPR 88->64
// and spilled (WRITE_SIZE 0.5->45MB, FETCH 26->92MB, lstm 52->64us). Keep grid
// 1024 (4 blocks/CU at <=128 VGPR), double-buffered xs/cs (1 barrier/iter),
// deferred y-epilogue (yred[4][64][2], disjoint per-iter slices, single
// coalesced out phase at the end).

#define B_SIZE 65536

typedef __bf16 bf16x8 __attribute__((ext_vector_type(8)));
typedef __bf16 bf16x4 __attribute__((ext_vector_type(4)));
typedef float f32x4 __attribute__((ext_vector_type(4)));

__device__ __forceinline__ float fsig(float x) {
    float e = __builtin_amdgcn_exp2f(-1.442695040888963f * x);
    return __builtin_amdgcn_rcpf(1.0f + e);
}
__device__ __forceinline__ float ftanh(float x) {
    float e = __builtin_amdgcn_exp2f(2.885390081777927f * x);
    return 1.0f - 2.0f * __builtin_amdgcn_rcpf(e + 1.0f);
}

// bias512[g*128+r] = bx_g[r] + sum_k h0[k] * Wh_g[r][k]
__global__ void bias_kernel(const float* __restrict__ h0,
                            const float* __restrict__ Whf, const float* __restrict__ Whi,
                            const float* __restrict__ Who, const float* __restrict__ Whc,
                            const float* __restrict__ bxf, const float* __restrict__ bxi,
                            const float* __restrict__ bxo, const float* __restrict__ bxc,
                            float* __restrict__ bias512) {
    int j = blockIdx.x * 64 + threadIdx.x;   // 8 blocks x 64 threads = 512
    int g = j >> 7, r = j & 127;
    const float* Wh = (g == 0) ? Whf : (g == 1) ? Whi : (g == 2) ? Who : Whc;
    const float* bx = (g == 0) ? bxf : (g == 1) ? bxi : (g == 2) ? bxo : bxc;
    float s = bx[r];
    const float4* row = (const float4*)(Wh + r * 128);
    const float4* h4  = (const float4*)h0;
#pragma unroll 8
    for (int k = 0; k < 32; ++k) {
        float4 a = row[k], b = h4[k];
        s += a.x * b.x + a.y * b.y + a.z * b.z + a.w * b.w;
    }
    bias512[j] = s;
}

__launch_bounds__(256, 2)
__global__ void lstm_kernel(const float* __restrict__ x, const float* __restrict__ c0,
                            const float* __restrict__ Wxf, const float* __restrict__ Wxi,
                            const float* __restrict__ Wxo, const float* __restrict__ Wxc,
                            const float* __restrict__ Wy, const float* __restrict__ by,
                            const float* __restrict__ bias512, float* __restrict__ out) {
    __shared__ __bf16 xs[2][1024];       // 16 rows x 64 k of x, A-fragment layout
    __shared__ float cs[2][16 * 132];    // 16 rows x 128 cols of c0, +4 pad/row
    __shared__ float yred[4][64][2];     // per-wave partial y, [w][it*16+row][o]

    const int tid  = threadIdx.x;
    const int lane = tid & 63;
    const int w    = tid >> 6;           // wave 0..3 -> hidden cols [w*32, w*32+32)
    const int q    = lane >> 4;          // quad: rows q*4..q*4+3 of the 16-row tile
    const int n15  = lane & 15;          // col within 16-col tile

    // ---- per-wave weight fragments (held in registers all kernel) ----
    const float* Wxg[4] = {Wxf, Wxi, Wxo, Wxc};
    bf16x8 bw[4][2][2];                  // [gate][colblock][kstep]
    float biasv[4][2];
#pragma unroll
    for (int g = 0; g < 4; ++g) {
#pragma unroll
        for (int cb = 0; cb < 2; ++cb) {
            const int n = w * 32 + cb * 16 + n15;    // hidden unit index
            biasv[g][cb] = bias512[g * 128 + n];
#pragma unroll
            for (int kb = 0; kb < 2; ++kb) {
                // B[k][n] = Wx_g[n][k]; lane holds k = kb*32 + q*8 + j
                const float* p = Wxg[g] + n * 64 + kb * 32 + q * 8;
                float4 lo = *(const float4*)p;
                float4 hi = *(const float4*)(p + 4);
                bf16x8 v;
                v[0] = (__bf16)lo.x; v[1] = (__bf16)lo.y; v[2] = (__bf16)lo.z; v[3] = (__bf16)lo.w;
                v[4] = (__bf16)hi.x; v[5] = (__bf16)hi.y; v[6] = (__bf16)hi.z; v[7] = (__bf16)hi.w;
                bw[g][cb][kb] = v;
            }
        }
    }
    float wyv[2][2];
#pragma unroll
    for (int o = 0; o < 2; ++o)
#pragma unroll
        for (int cb = 0; cb < 2; ++cb)
            wyv[o][cb] = Wy[o * 128 + w * 32 + cb * 16 + n15];
    const float by0 = by[0], by1 = by[1];

    constexpr int ITERS = (B_SIZE / 16) / 1024;  // 4 tiles of 16 rows per block
    const int tile0 = blockIdx.x * ITERS;        // contiguous 64 rows per block

    // x staging: thread t loads float4 of row (t>>4), k4=(t&15)*4 ; LDS index in
    // A-frag order: elem(m,k) -> (k>>5)*512 + ((k&31)>>3)*128 + m*8 + (k&7)
    const int xrow = tid >> 4;
    const int k4   = (tid & 15) * 4;
    const int sidx = (k4 >> 5) * 512 + ((k4 & 31) >> 3) * 128 + xrow * 8 + (k4 & 7);

    // c0 staging: thread t loads 8 consecutive floats of row (t>>4), cols (t&15)*8
    const int ccol = (tid & 15) * 8;
    const int cidx = xrow * 132 + ccol;

    // ---- prologue: tile0 -> buf0; prefetch tile1 into regs ----
    float4 xr  = *(const float4*)(x  + (size_t)(tile0 * 16 + xrow) * 64 + k4);
    float4 cpa = *(const float4*)(c0 + (size_t)(tile0 * 16 + xrow) * 128 + ccol);
    float4 cpb = *(const float4*)(c0 + (size_t)(tile0 * 16 + xrow) * 128 + ccol + 4);
    {
        bf16x4 v; v[0] = (__bf16)xr.x; v[1] = (__bf16)xr.y; v[2] = (__bf16)xr.z; v[3] = (__bf16)xr.w;
        *(bf16x4*)&xs[0][sidx] = v;
        *(float4*)&cs[0][cidx] = cpa;
        *(float4*)&cs[0][cidx + 4] = cpb;
    }
    xr  = *(const float4*)(x  + (size_t)((tile0 + 1) * 16 + xrow) * 64 + k4);
    cpa = *(const float4*)(c0 + (size_t)((tile0 + 1) * 16 + xrow) * 128 + ccol);
    cpb = *(const float4*)(c0 + (size_t)((tile0 + 1) * 16 + xrow) * 128 + ccol + 4);
    __syncthreads();

#pragma unroll
    for (int it = 0; it < ITERS; ++it) {
        const int cur = it & 1;

        // A fragments (shared by all 4 waves)
        bf16x8 a0 = *(const bf16x8*)&xs[cur][lane * 8];
        bf16x8 a1 = *(const bf16x8*)&xs[cur][512 + lane * 8];

        // c0 from LDS: lane needs (row q*4+r, col w*32+cb*16+n15); 2-way bank alias (free)
        float c0v[2][4];
#pragma unroll
        for (int cb = 0; cb < 2; ++cb)
#pragma unroll
            for (int r = 0; r < 4; ++r)
                c0v[cb][r] = cs[cur][(q * 4 + r) * 132 + w * 32 + cb * 16 + n15];

        // stage tile it+1 (held in regs) into the other buffer; then prefetch it+2
        if (it + 1 < ITERS) {
            bf16x4 v; v[0] = (__bf16)xr.x; v[1] = (__bf16)xr.y; v[2] = (__bf16)xr.z; v[3] = (__bf16)xr.w;
            *(bf16x4*)&xs[cur ^ 1][sidx] = v;
            *(float4*)&cs[cur ^ 1][cidx] = cpa;
            *(float4*)&cs[cur ^ 1][cidx + 4] = cpb;
            if (it + 2 < ITERS) {
                const int tn = tile0 + it + 2;
                xr  = *(const float4*)(x  + (size_t)(tn * 16 + xrow) * 64 + k4);
                cpa = *(const float4*)(c0 + (size_t)(tn * 16 + xrow) * 128 + ccol);
                cpb = *(const float4*)(c0 + (size_t)(tn * 16 + xrow) * 128 + ccol + 4);
            }
        }

        // MFMA: acc initialized with bias (bias depends only on col)
        f32x4 acc[4][2];
#pragma unroll
        for (int g = 0; g < 4; ++g)
#pragma unroll
            for (int cb = 0; cb < 2; ++cb) {
                float b = biasv[g][cb];
                f32x4 t = {b, b, b, b};
                acc[g][cb] = t;
            }
#pragma unroll
        for (int g = 0; g < 4; ++g)
#pragma unroll
            for (int cb = 0; cb < 2; ++cb) {
                acc[g][cb] = __builtin_amdgcn_mfma_f32_16x16x32_bf16(a0, bw[g][cb][0], acc[g][cb], 0, 0, 0);
                acc[g][cb] = __builtin_amdgcn_mfma_f32_16x16x32_bf16(a1, bw[g][cb][1], acc[g][cb], 0, 0, 0);
            }

        // elementwise epilogue; C/D layout: col=lane&15, row=q*4+reg
        float p0[4] = {0.f, 0.f, 0.f, 0.f};
        float p1[4] = {0.f, 0.f, 0.f, 0.f};
#pragma unroll
        for (int cb = 0; cb < 2; ++cb)
#pragma unroll
            for (int r = 0; r < 4; ++r) {
                float fg = fsig(acc[0][cb][r]);
                float ig = fsig(acc[1][cb][r]);
                float og = fsig(acc[2][cb][r]);
                float ct = ftanh(acc[3][cb][r]);
                float c  = fg * c0v[cb][r] + ig * ct;
                float h  = og * ftanh(c);
                p0[r] += h * wyv[0][cb];
                p1[r] += h * wyv[1][cb];
            }
        // reduce over the 16 lanes of each quad group (cols of this wave)
#pragma unroll
        for (int m = 1; m < 16; m <<= 1) {
#pragma unroll
            for (int r = 0; r < 4; ++r) {
                p0[r] += __shfl_xor(p0[r], m, 64);
                p1[r] += __shfl_xor(p1[r], m, 64);
            }
        }
        if (n15 == 0) {
#pragma unroll
            for (int r = 0; r < 4; ++r) {
                yred[w][it * 16 + q * 4 + r][0] = p0[r];
                yred[w][it * 16 + q * 4 + r][1] = p1[r];
            }
        }
        __syncthreads();
    }

    // ---- final out phase: 64 contiguous rows, coalesced float2 stores ----
    if (tid < 64) {
        float s0 = by0 + yred[0][tid][0] + yred[1][tid][0] + yred[2][tid][0] + yred[3][tid][0];
        float s1 = by1 + yred[0][tid][1] + yred[1][tid][1] + yred[2][tid][1] + yred[3][tid][1];
        float2 s = {s0, s1};
        *(float2*)(out + (size_t)(tile0 * 16 + tid) * 2) = s;
    }
}

extern "C" void kernel_launch(void* const* d_in, const int* in_sizes, int n_in,
                              void* d_out, int out_size, void* d_ws, size_t ws_size,
                              hipStream_t stream) {
    // setup_inputs order: x, h0, c0, [Wxf,bxf,Whf], [Wxi,bxi,Whi], [Wxo,bxo,Who],
    //                     [Wxc,bxc,Whc], Wy, by
    const float* x   = (const float*)d_in[0];
    const float* h0  = (const float*)d_in[1];
    const float* c0  = (const float*)d_in[2];
    const float* Wxf = (const float*)d_in[3];
    const float* bxf = (const float*)d_in[4];
    const float* Whf = (const float*)d_in[5];
    const float* Wxi = (const float*)d_in[6];
    const float* bxi = (const float*)d_in[7];
    const float* Whi = (const float*)d_in[8];
    const float* Wxo = (const float*)d_in[9];
    const float* bxo = (const float*)d_in[10];
    const float* Who = (const float*)d_in[11];
    const float* Wxc = (const float*)d_in[12];
    const float* bxc = (const float*)d_in[13];
    const float* Whc = (const float*)d_in[14];
    const float* Wy  = (const float*)d_in[15];
    const float* by  = (const float*)d_in[16];
    float* out = (float*)d_out;
    float* bias512 = (float*)d_ws;   // 512 floats scratch

    bias_kernel<<<8, 64, 0, stream>>>(h0, Whf, Whi, Who, Whc, bxf, bxi, bxo, bxc, bias512);
    lstm_kernel<<<1024, 256, 0, stream>>>(x, c0, Wxf, Wxi, Wxo, Wxc, Wy, by, bias512, out);
}

// Round 4
// 126.119 us; speedup vs baseline: 1.2924x; 1.0781x over previous
//
#include <hip/hip_runtime.h>

// LSTM classifier single step: B=65536, IN=64, H=128, OUT=2.
// Harness facts (R0-R3): 256 MiB d_ws re-poison fill is unconditional, ~94us
// of every timed iteration — using d_ws is free. lstm stuck at ~40us across
// R0/R3 structural changes; dominant non-mandatory traffic = per-block Wx f32
// prologue (1024 x 128 KB = 134 MB vs 51 MB mandatory x/c0).
// R4: prep_kernel pre-converts Wx into per-(wave,gate,cb,kb,lane) bf16x8 MFMA
// fragments in d_ws — lstm prologue = 16 coalesced dwordx4 loads/lane, no cvt.
// Grid 512 x ITERS 8 (all blocks resident, weight traffic 32 MB total).
// Main loop unchanged from R3: dbuf xs/cs, 1 barrier/iter, deferred y-epilogue.

#define B_SIZE 65536

typedef __bf16 bf16x8 __attribute__((ext_vector_type(8)));
typedef __bf16 bf16x4 __attribute__((ext_vector_type(4)));
typedef float f32x4 __attribute__((ext_vector_type(4)));

__device__ __forceinline__ float fsig(float x) {
    float e = __builtin_amdgcn_exp2f(-1.442695040888963f * x);
    return __builtin_amdgcn_rcpf(1.0f + e);
}
__device__ __forceinline__ float ftanh(float x) {
    float e = __builtin_amdgcn_exp2f(2.885390081777927f * x);
    return 1.0f - 2.0f * __builtin_amdgcn_rcpf(e + 1.0f);
}

// bias512[g*128+r] = bx_g[r] + sum_k h0[k] * Wh_g[r][k]
__global__ void bias_kernel(const float* __restrict__ h0,
                            const float* __restrict__ Whf, const float* __restrict__ Whi,
                            const float* __restrict__ Who, const float* __restrict__ Whc,
                            const float* __restrict__ bxf, const float* __restrict__ bxi,
                            const float* __restrict__ bxo, const float* __restrict__ bxc,
                            float* __restrict__ bias512) {
    int j = blockIdx.x * 64 + threadIdx.x;   // 8 blocks x 64 threads = 512
    int g = j >> 7, r = j & 127;
    const float* Wh = (g == 0) ? Whf : (g == 1) ? Whi : (g == 2) ? Who : Whc;
    const float* bx = (g == 0) ? bxf : (g == 1) ? bxi : (g == 2) ? bxo : bxc;
    float s = bx[r];
    const float4* row = (const float4*)(Wh + r * 128);
    const float4* h4  = (const float4*)h0;
#pragma unroll 8
    for (int k = 0; k < 32; ++k) {
        float4 a = row[k], b = h4[k];
        s += a.x * b.x + a.y * b.y + a.z * b.z + a.w * b.w;
    }
    bias512[j] = s;
}

// frags[t*8 + j], t = w*1024 + g*256 + cb*128 + kb*64 + lane :
//   bf16( Wx_g[(w*32+cb*16+(lane&15))*64 + kb*32 + (lane>>4)*8 + j] )
// Matches lstm's per-lane B-fragment: lane holds k = kb*32 + q*8 + j of
// hidden unit n = w*32 + cb*16 + n15.
__global__ void prep_kernel(const float* __restrict__ Wxf, const float* __restrict__ Wxi,
                            const float* __restrict__ Wxo, const float* __restrict__ Wxc,
                            __bf16* __restrict__ frags) {
    int t = blockIdx.x * 64 + threadIdx.x;   // 64 blocks x 64 threads = 4096
    int w    = t >> 10;
    int g    = (t >> 8) & 3;
    int cb   = (t >> 7) & 1;
    int kb   = (t >> 6) & 1;
    int lane = t & 63;
    const float* Wx = (g == 0) ? Wxf : (g == 1) ? Wxi : (g == 2) ? Wxo : Wxc;
    const int n = w * 32 + cb * 16 + (lane & 15);
    const float* p = Wx + n * 64 + kb * 32 + (lane >> 4) * 8;
    float4 lo = *(const float4*)p;
    float4 hi = *(const float4*)(p + 4);
    bf16x8 v;
    v[0] = (__bf16)lo.x; v[1] = (__bf16)lo.y; v[2] = (__bf16)lo.z; v[3] = (__bf16)lo.w;
    v[4] = (__bf16)hi.x; v[5] = (__bf16)hi.y; v[6] = (__bf16)hi.z; v[7] = (__bf16)hi.w;
    *(bf16x8*)(frags + (size_t)t * 8) = v;
}

__launch_bounds__(256, 2)
__global__ void lstm_kernel(const float* __restrict__ x, const float* __restrict__ c0,
                            const __bf16* __restrict__ frags,
                            const float* __restrict__ Wy, const float* __restrict__ by,
                            const float* __restrict__ bias512, float* __restrict__ out) {
    __shared__ __bf16 xs[2][1024];       // 16 rows x 64 k of x, A-fragment layout
    __shared__ float cs[2][16 * 132];    // 16 rows x 128 cols of c0, +4 pad/row
    __shared__ float yred[4][128][2];    // per-wave partial y, [w][it*16+row][o]

    const int tid  = threadIdx.x;
    const int lane = tid & 63;
    const int w    = tid >> 6;           // wave 0..3 -> hidden cols [w*32, w*32+32)
    const int q    = lane >> 4;          // quad: rows q*4..q*4+3 of the 16-row tile
    const int n15  = lane & 15;          // col within 16-col tile

    // ---- prologue: pre-built bf16 fragments, coalesced 16B/lane loads ----
    bf16x8 bw[4][2][2];                  // [gate][colblock][kstep]
    float biasv[4][2];
#pragma unroll
    for (int g = 0; g < 4; ++g)
#pragma unroll
        for (int cb = 0; cb < 2; ++cb) {
            biasv[g][cb] = bias512[g * 128 + w * 32 + cb * 16 + n15];
#pragma unroll
            for (int kb = 0; kb < 2; ++kb)
                bw[g][cb][kb] = *(const bf16x8*)(frags +
                    (size_t)(((w * 16 + g * 4 + cb * 2 + kb) * 64 + lane)) * 8);
        }
    float wyv[2][2];
#pragma unroll
    for (int o = 0; o < 2; ++o)
#pragma unroll
        for (int cb = 0; cb < 2; ++cb)
            wyv[o][cb] = Wy[o * 128 + w * 32 + cb * 16 + n15];
    const float by0 = by[0], by1 = by[1];

    constexpr int ITERS = (B_SIZE / 16) / 512;   // 8 tiles of 16 rows per block
    const int tile0 = blockIdx.x * ITERS;        // contiguous 128 rows per block

    // x staging: thread t loads float4 of row (t>>4), k4=(t&15)*4 ; LDS index in
    // A-frag order: elem(m,k) -> (k>>5)*512 + ((k&31)>>3)*128 + m*8 + (k&7)
    const int xrow = tid >> 4;
    const int k4   = (tid & 15) * 4;
    const int sidx = (k4 >> 5) * 512 + ((k4 & 31) >> 3) * 128 + xrow * 8 + (k4 & 7);

    // c0 staging: thread t loads 8 consecutive floats of row (t>>4), cols (t&15)*8
    const int ccol = (tid & 15) * 8;
    const int cidx = xrow * 132 + ccol;

    // ---- prologue: tile0 -> buf0; prefetch tile1 into regs ----
    float4 xr  = *(const float4*)(x  + (size_t)(tile0 * 16 + xrow) * 64 + k4);
    float4 cpa = *(const float4*)(c0 + (size_t)(tile0 * 16 + xrow) * 128 + ccol);
    float4 cpb = *(const float4*)(c0 + (size_t)(tile0 * 16 + xrow) * 128 + ccol + 4);
    {
        bf16x4 v; v[0] = (__bf16)xr.x; v[1] = (__bf16)xr.y; v[2] = (__bf16)xr.z; v[3] = (__bf16)xr.w;
        *(bf16x4*)&xs[0][sidx] = v;
        *(float4*)&cs[0][cidx] = cpa;
        *(float4*)&cs[0][cidx + 4] = cpb;
    }
    xr  = *(const float4*)(x  + (size_t)((tile0 + 1) * 16 + xrow) * 64 + k4);
    cpa = *(const float4*)(c0 + (size_t)((tile0 + 1) * 16 + xrow) * 128 + ccol);
    cpb = *(const float4*)(c0 + (size_t)((tile0 + 1) * 16 + xrow) * 128 + ccol + 4);
    __syncthreads();

#pragma unroll
    for (int it = 0; it < ITERS; ++it) {
        const int cur = it & 1;

        // A fragments (shared by all 4 waves)
        bf16x8 a0 = *(const bf16x8*)&xs[cur][lane * 8];
        bf16x8 a1 = *(const bf16x8*)&xs[cur][512 + lane * 8];

        // c0 from LDS: lane needs (row q*4+r, col w*32+cb*16+n15); 2-way bank alias (free)
        float c0v[2][4];
#pragma unroll
        for (int cb = 0; cb < 2; ++cb)
#pragma unroll
            for (int r = 0; r < 4; ++r)
                c0v[cb][r] = cs[cur][(q * 4 + r) * 132 + w * 32 + cb * 16 + n15];

        // stage tile it+1 (held in regs) into the other buffer; then prefetch it+2
        if (it + 1 < ITERS) {
            bf16x4 v; v[0] = (__bf16)xr.x; v[1] = (__bf16)xr.y; v[2] = (__bf16)xr.z; v[3] = (__bf16)xr.w;
            *(bf16x4*)&xs[cur ^ 1][sidx] = v;
            *(float4*)&cs[cur ^ 1][cidx] = cpa;
            *(float4*)&cs[cur ^ 1][cidx + 4] = cpb;
            if (it + 2 < ITERS) {
                const int tn = tile0 + it + 2;
                xr  = *(const float4*)(x  + (size_t)(tn * 16 + xrow) * 64 + k4);
                cpa = *(const float4*)(c0 + (size_t)(tn * 16 + xrow) * 128 + ccol);
                cpb = *(const float4*)(c0 + (size_t)(tn * 16 + xrow) * 128 + ccol + 4);
            }
        }

        // MFMA: acc initialized with bias (bias depends only on col)
        f32x4 acc[4][2];
#pragma unroll
        for (int g = 0; g < 4; ++g)
#pragma unroll
            for (int cb = 0; cb < 2; ++cb) {
                float b = biasv[g][cb];
                f32x4 t = {b, b, b, b};
                acc[g][cb] = t;
            }
#pragma unroll
        for (int g = 0; g < 4; ++g)
#pragma unroll
            for (int cb = 0; cb < 2; ++cb) {
                acc[g][cb] = __builtin_amdgcn_mfma_f32_16x16x32_bf16(a0, bw[g][cb][0], acc[g][cb], 0, 0, 0);
                acc[g][cb] = __builtin_amdgcn_mfma_f32_16x16x32_bf16(a1, bw[g][cb][1], acc[g][cb], 0, 0, 0);
            }

        // elementwise epilogue; C/D layout: col=lane&15, row=q*4+reg
        float p0[4] = {0.f, 0.f, 0.f, 0.f};
        float p1[4] = {0.f, 0.f, 0.f, 0.f};
#pragma unroll
        for (int cb = 0; cb < 2; ++cb)
#pragma unroll
            for (int r = 0; r < 4; ++r) {
                float fg = fsig(acc[0][cb][r]);
                float ig = fsig(acc[1][cb][r]);
                float og = fsig(acc[2][cb][r]);
                float ct = ftanh(acc[3][cb][r]);
                float c  = fg * c0v[cb][r] + ig * ct;
                float h  = og * ftanh(c);
                p0[r] += h * wyv[0][cb];
                p1[r] += h * wyv[1][cb];
            }
        // reduce over the 16 lanes of each quad group (cols of this wave)
#pragma unroll
        for (int m = 1; m < 16; m <<= 1) {
#pragma unroll
            for (int r = 0; r < 4; ++r) {
                p0[r] += __shfl_xor(p0[r], m, 64);
                p1[r] += __shfl_xor(p1[r], m, 64);
            }
        }
        if (n15 == 0) {
#pragma unroll
            for (int r = 0; r < 4; ++r) {
                yred[w][it * 16 + q * 4 + r][0] = p0[r];
                yred[w][it * 16 + q * 4 + r][1] = p1[r];
            }
        }
        __syncthreads();
    }

    // ---- final out phase: 128 contiguous rows, coalesced float2 stores ----
    if (tid < 128) {
        float s0 = by0 + yred[0][tid][0] + yred[1][tid][0] + yred[2][tid][0] + yred[3][tid][0];
        float s1 = by1 + yred[0][tid][1] + yred[1][tid][1] + yred[2][tid][1] + yred[3][tid][1];
        float2 s = {s0, s1};
        *(float2*)(out + (size_t)(tile0 * 16 + tid) * 2) = s;
    }
}

extern "C" void kernel_launch(void* const* d_in, const int* in_sizes, int n_in,
                              void* d_out, int out_size, void* d_ws, size_t ws_size,
                              hipStream_t stream) {
    // setup_inputs order: x, h0, c0, [Wxf,bxf,Whf], [Wxi,bxi,Whi], [Wxo,bxo,Who],
    //                     [Wxc,bxc,Whc], Wy, by
    const float* x   = (const float*)d_in[0];
    const float* h0  = (const float*)d_in[1];
    const float* c0  = (const float*)d_in[2];
    const float* Wxf = (const float*)d_in[3];
    const float* bxf = (const float*)d_in[4];
    const float* Whf = (const float*)d_in[5];
    const float* Wxi = (const float*)d_in[6];
    const float* bxi = (const float*)d_in[7];
    const float* Whi = (const float*)d_in[8];
    const float* Wxo = (const float*)d_in[9];
    const float* bxo = (const float*)d_in[10];
    const float* Who = (const float*)d_in[11];
    const float* Wxc = (const float*)d_in[12];
    const float* bxc = (const float*)d_in[13];
    const float* Whc = (const float*)d_in[14];
    const float* Wy  = (const float*)d_in[15];
    const float* by  = (const float*)d_in[16];
    float* out = (float*)d_out;
    float* bias512 = (float*)d_ws;                   // 512 floats
    __bf16* frags  = (__bf16*)((float*)d_ws + 512);  // 4096 x bf16x8 = 64 KB

    bias_kernel<<<8, 64, 0, stream>>>(h0, Whf, Whi, Who, Whc, bxf, bxi, bxo, bxc, bias512);
    prep_kernel<<<64, 64, 0, stream>>>(Wxf, Wxi, Wxo, Wxc, frags);
    lstm_kernel<<<512, 256, 0, stream>>>(x, c0, frags, Wy, by, bias512, out);
}

// Round 5
// 125.537 us; speedup vs baseline: 1.2983x; 1.0046x over previous
//
#include <hip/hip_runtime.h>

// LSTM classifier single step: B=65536, IN=64, H=128, OUT=2.
// Harness facts (R0-R4): 256 MiB d_ws re-poison fill is unconditional (~94us
// per timed iter) — d_ws use is free. lstm trajectory: 52 (R1) -> 40 (R3) ->
// ~28 (R4, pre-built bf16 weight frags in ws). R1 counters: 525 GB/s, VALU 20%,
// occ 19% => latency-bound at 8 waves/CU (grid 512 x 256thr = 2 blocks/CU).
// R5: 512-thread blocks (8 waves: 2 row-halves x 4 col-groups per 32-row tile),
// grid 512, ITERS 4 -> 16 waves/CU at VGPR~88. prep+bias merged into 1 kernel.

#define B_SIZE 65536

typedef __bf16 bf16x8 __attribute__((ext_vector_type(8)));
typedef __bf16 bf16x4 __attribute__((ext_vector_type(4)));
typedef float f32x4 __attribute__((ext_vector_type(4)));

__device__ __forceinline__ float fsig(float x) {
    float e = __builtin_amdgcn_exp2f(-1.442695040888963f * x);
    return __builtin_amdgcn_rcpf(1.0f + e);
}
__device__ __forceinline__ float ftanh(float x) {
    float e = __builtin_amdgcn_exp2f(2.885390081777927f * x);
    return 1.0f - 2.0f * __builtin_amdgcn_rcpf(e + 1.0f);
}

// blocks 0..7:  bias512[g*128+r] = bx_g[r] + sum_k h0[k] * Wh_g[r][k]
// blocks 8..71: frags[t*8+j] = bf16(Wx_g[(w*32+cb*16+(lane&15))*64 + kb*32 +
//               (lane>>4)*8 + j]), t = w*1024+g*256+cb*128+kb*64+lane
__global__ void prep_kernel(const float* __restrict__ h0,
                            const float* __restrict__ Whf, const float* __restrict__ Whi,
                            const float* __restrict__ Who, const float* __restrict__ Whc,
                            const float* __restrict__ bxf, const float* __restrict__ bxi,
                            const float* __restrict__ bxo, const float* __restrict__ bxc,
                            const float* __restrict__ Wxf, const float* __restrict__ Wxi,
                            const float* __restrict__ Wxo, const float* __restrict__ Wxc,
                            float* __restrict__ bias512, __bf16* __restrict__ frags) {
    if (blockIdx.x < 8) {
        int j = blockIdx.x * 64 + threadIdx.x;   // 512 bias entries
        int g = j >> 7, r = j & 127;
        const float* Wh = (g == 0) ? Whf : (g == 1) ? Whi : (g == 2) ? Who : Whc;
        const float* bx = (g == 0) ? bxf : (g == 1) ? bxi : (g == 2) ? bxo : bxc;
        float s = bx[r];
        const float4* row = (const float4*)(Wh + r * 128);
        const float4* h4  = (const float4*)h0;
#pragma unroll 8
        for (int k = 0; k < 32; ++k) {
            float4 a = row[k], b = h4[k];
            s += a.x * b.x + a.y * b.y + a.z * b.z + a.w * b.w;
        }
        bias512[j] = s;
    } else {
        int t = (blockIdx.x - 8) * 64 + threadIdx.x;   // 4096 fragment slots
        int w    = t >> 10;
        int g    = (t >> 8) & 3;
        int cb   = (t >> 7) & 1;
        int kb   = (t >> 6) & 1;
        int lane = t & 63;
        const float* Wx = (g == 0) ? Wxf : (g == 1) ? Wxi : (g == 2) ? Wxo : Wxc;
        const int n = w * 32 + cb * 16 + (lane & 15);
        const float* p = Wx + n * 64 + kb * 32 + (lane >> 4) * 8;
        float4 lo = *(const float4*)p;
        float4 hi = *(const float4*)(p + 4);
        bf16x8 v;
        v[0] = (__bf16)lo.x; v[1] = (__bf16)lo.y; v[2] = (__bf16)lo.z; v[3] = (__bf16)lo.w;
        v[4] = (__bf16)hi.x; v[5] = (__bf16)hi.y; v[6] = (__bf16)hi.z; v[7] = (__bf16)hi.w;
        *(bf16x8*)(frags + (size_t)t * 8) = v;
    }
}

__launch_bounds__(512, 2)
__global__ void lstm_kernel(const float* __restrict__ x, const float* __restrict__ c0,
                            const __bf16* __restrict__ frags,
                            const float* __restrict__ Wy, const float* __restrict__ by,
                            const float* __restrict__ bias512, float* __restrict__ out) {
    __shared__ __bf16 xs[2][2][1024];    // [buf][rowhalf][16x64 A-frag layout]
    __shared__ float cs[2][32 * 132];    // [buf][32 rows x 128 cols, +4 pad/row]
    __shared__ float yred[4][128][2];    // [colgroup][block row][o]

    const int tid  = threadIdx.x;
    const int lane = tid & 63;
    const int w    = tid >> 6;           // wave 0..7
    const int rh   = w >> 2;             // row half: rows rh*16 .. rh*16+16 of tile
    const int wc   = w & 3;              // col group: cols wc*32 .. wc*32+32
    const int q    = lane >> 4;          // quad: rows q*4..q*4+3 within 16-row half
    const int n15  = lane & 15;          // col within 16-col tile

    // ---- prologue: pre-built bf16 fragments, coalesced 16B/lane loads ----
    bf16x8 bw[4][2][2];                  // [gate][colblock][kstep]
    float biasv[4][2];
#pragma unroll
    for (int g = 0; g < 4; ++g)
#pragma unroll
        for (int cb = 0; cb < 2; ++cb) {
            biasv[g][cb] = bias512[g * 128 + wc * 32 + cb * 16 + n15];
#pragma unroll
            for (int kb = 0; kb < 2; ++kb)
                bw[g][cb][kb] = *(const bf16x8*)(frags +
                    (size_t)(((wc * 16 + g * 4 + cb * 2 + kb) * 64 + lane)) * 8);
        }
    float wyv[2][2];
#pragma unroll
    for (int o = 0; o < 2; ++o)
#pragma unroll
        for (int cb = 0; cb < 2; ++cb)
            wyv[o][cb] = Wy[o * 128 + wc * 32 + cb * 16 + n15];
    const float by0 = by[0], by1 = by[1];

    constexpr int ITERS = (B_SIZE / 32) / 512;   // 4 tiles of 32 rows per block
    const int row0 = blockIdx.x * (ITERS * 32);  // contiguous 128 rows per block

    // x staging: thread t loads float4 of row (t>>4) in [0,32), k4=(t&15)*4.
    // Within each 16-row half, A-frag order: elem(m,k) -> (k>>5)*512 +
    // ((k&31)>>3)*128 + m*8 + (k&7)
    const int xrow = tid >> 4;
    const int k4   = (tid & 15) * 4;
    const int rhs  = xrow >> 4;
    const int sidx = (k4 >> 5) * 512 + ((k4 & 31) >> 3) * 128 + (xrow & 15) * 8 + (k4 & 7);

    // c0 staging: thread t loads 8 consecutive floats of row (t>>4), cols (t&15)*8
    const int ccol = (tid & 15) * 8;
    const int cidx = xrow * 132 + ccol;

    // ---- prologue: tile0 -> buf0; prefetch tile1 into regs ----
    float4 xr  = *(const float4*)(x  + (size_t)(row0 + xrow) * 64 + k4);
    float4 cpa = *(const float4*)(c0 + (size_t)(row0 + xrow) * 128 + ccol);
    float4 cpb = *(const float4*)(c0 + (size_t)(row0 + xrow) * 128 + ccol + 4);
    {
        bf16x4 v; v[0] = (__bf16)xr.x; v[1] = (__bf16)xr.y; v[2] = (__bf16)xr.z; v[3] = (__bf16)xr.w;
        *(bf16x4*)&xs[0][rhs][sidx] = v;
        *(float4*)&cs[0][cidx] = cpa;
        *(float4*)&cs[0][cidx + 4] = cpb;
    }
    xr  = *(const float4*)(x  + (size_t)(row0 + 32 + xrow) * 64 + k4);
    cpa = *(const float4*)(c0 + (size_t)(row0 + 32 + xrow) * 128 + ccol);
    cpb = *(const float4*)(c0 + (size_t)(row0 + 32 + xrow) * 128 + ccol + 4);
    __syncthreads();

#pragma unroll
    for (int it = 0; it < ITERS; ++it) {
        const int cur = it & 1;

        // A fragments for this wave's row half
        bf16x8 a0 = *(const bf16x8*)&xs[cur][rh][lane * 8];
        bf16x8 a1 = *(const bf16x8*)&xs[cur][rh][512 + lane * 8];

        // c0 from LDS: (row rh*16+q*4+r, col wc*32+cb*16+n15); 2-way bank alias (free)
        float c0v[2][4];
#pragma unroll
        for (int cb = 0; cb < 2; ++cb)
#pragma unroll
            for (int r = 0; r < 4; ++r)
                c0v[cb][r] = cs[cur][(rh * 16 + q * 4 + r) * 132 + wc * 32 + cb * 16 + n15];

        // stage tile it+1 (held in regs) into the other buffer; then prefetch it+2
        if (it + 1 < ITERS) {
            bf16x4 v; v[0] = (__bf16)xr.x; v[1] = (__bf16)xr.y; v[2] = (__bf16)xr.z; v[3] = (__bf16)xr.w;
            *(bf16x4*)&xs[cur ^ 1][rhs][sidx] = v;
            *(float4*)&cs[cur ^ 1][cidx] = cpa;
            *(float4*)&cs[cur ^ 1][cidx + 4] = cpb;
            if (it + 2 < ITERS) {
                const int rn = row0 + (it + 2) * 32;
                xr  = *(const float4*)(x  + (size_t)(rn + xrow) * 64 + k4);
                cpa = *(const float4*)(c0 + (size_t)(rn + xrow) * 128 + ccol);
                cpb = *(const float4*)(c0 + (size_t)(rn + xrow) * 128 + ccol + 4);
            }
        }

        // MFMA: acc initialized with bias (bias depends only on col)
        f32x4 acc[4][2];
#pragma unroll
        for (int g = 0; g < 4; ++g)
#pragma unroll
            for (int cb = 0; cb < 2; ++cb) {
                float b = biasv[g][cb];
                f32x4 t = {b, b, b, b};
                acc[g][cb] = t;
            }
#pragma unroll
        for (int g = 0; g < 4; ++g)
#pragma unroll
            for (int cb = 0; cb < 2; ++cb) {
                acc[g][cb] = __builtin_amdgcn_mfma_f32_16x16x32_bf16(a0, bw[g][cb][0], acc[g][cb], 0, 0, 0);
                acc[g][cb] = __builtin_amdgcn_mfma_f32_16x16x32_bf16(a1, bw[g][cb][1], acc[g][cb], 0, 0, 0);
            }

        // elementwise epilogue; C/D layout: col=lane&15, row=q*4+reg
        float p0[4] = {0.f, 0.f, 0.f, 0.f};
        float p1[4] = {0.f, 0.f, 0.f, 0.f};
#pragma unroll
        for (int cb = 0; cb < 2; ++cb)
#pragma unroll
            for (int r = 0; r < 4; ++r) {
                float fg = fsig(acc[0][cb][r]);
                float ig = fsig(acc[1][cb][r]);
                float og = fsig(acc[2][cb][r]);
                float ct = ftanh(acc[3][cb][r]);
                float c  = fg * c0v[cb][r] + ig * ct;
                float h  = og * ftanh(c);
                p0[r] += h * wyv[0][cb];
                p1[r] += h * wyv[1][cb];
            }
        // reduce over the 16 lanes of each quad group (cols of this wave)
#pragma unroll
        for (int m = 1; m < 16; m <<= 1) {
#pragma unroll
            for (int r = 0; r < 4; ++r) {
                p0[r] += __shfl_xor(p0[r], m, 64);
                p1[r] += __shfl_xor(p1[r], m, 64);
            }
        }
        if (n15 == 0) {
#pragma unroll
            for (int r = 0; r < 4; ++r) {
                yred[wc][it * 32 + rh * 16 + q * 4 + r][0] = p0[r];
                yred[wc][it * 32 + rh * 16 + q * 4 + r][1] = p1[r];
            }
        }
        __syncthreads();
    }

    // ---- final out phase: 128 contiguous rows, coalesced float2 stores ----
    if (tid < 128) {
        float s0 = by0 + yred[0][tid][0] + yred[1][tid][0] + yred[2][tid][0] + yred[3][tid][0];
        float s1 = by1 + yred[0][tid][1] + yred[1][tid][1] + yred[2][tid][1] + yred[3][tid][1];
        float2 s = {s0, s1};
        *(float2*)(out + (size_t)(row0 + tid) * 2) = s;
    }
}

extern "C" void kernel_launch(void* const* d_in, const int* in_sizes, int n_in,
                              void* d_out, int out_size, void* d_ws, size_t ws_size,
                              hipStream_t stream) {
    // setup_inputs order: x, h0, c0, [Wxf,bxf,Whf], [Wxi,bxi,Whi], [Wxo,bxo,Who],
    //                     [Wxc,bxc,Whc], Wy, by
    const float* x   = (const float*)d_in[0];
    const float* h0  = (const float*)d_in[1];
    const float* c0  = (const float*)d_in[2];
    const float* Wxf = (const float*)d_in[3];
    const float* bxf = (const float*)d_in[4];
    const float* Whf = (const float*)d_in[5];
    const float* Wxi = (const float*)d_in[6];
    const float* bxi = (const float*)d_in[7];
    const float* Whi = (const float*)d_in[8];
    const float* Wxo = (const float*)d_in[9];
    const float* bxo = (const float*)d_in[10];
    const float* Who = (const float*)d_in[11];
    const float* Wxc = (const float*)d_in[12];
    const float* bxc = (const float*)d_in[13];
    const float* Whc = (const float*)d_in[14];
    const float* Wy  = (const float*)d_in[15];
    const float* by  = (const float*)d_in[16];
    float* out = (float*)d_out;
    float* bias512 = (float*)d_ws;                   // 512 floats
    __bf16* frags  = (__bf16*)((float*)d_ws + 512);  // 4096 x bf16x8 = 64 KB

    prep_kernel<<<72, 64, 0, stream>>>(h0, Whf, Whi, Who, Whc, bxf, bxi, bxo, bxc,
                                       Wxf, Wxi, Wxo, Wxc, bias512, frags);
    lstm_kernel<<<512, 512, 0, stream>>>(x, c0, frags, Wy, by, bias512, out);
}